// Round 1
// baseline (169.369 us; speedup 1.0000x reference)
//
#include <hip/hip_runtime.h>

#define H 512
#define W 512
#define BATCH 32
#define KS 5
#define B_CHUNK 8   // batches per thread; 32/8 = 4 chunks across grid.x

// Each thread: fixed (h, w0..w0+3), caches 25 float4 kernel taps in regs,
// loops over 8 batches. 128 threads cover one row of W=512; block=256 covers
// 2 rows. Grid = (4 chunks, 256 row-pairs).
__global__ __launch_bounds__(256, 2) void op2d_kernel(
    const float* __restrict__ f,   // (B,H,W)
    const float* __restrict__ K,   // (5,5,H,W)
    const float* __restrict__ dt,  // (B,)
    float* __restrict__ out)       // (B,H,W)
{
    const int w0 = (threadIdx.x & 127) * 4;                 // 0..508, mult of 4
    const int h  = blockIdx.y * 2 + (threadIdx.x >> 7);     // 0..511
    const int chunk = blockIdx.x;                           // 0..3

    // ---- load 25 per-pixel kernel taps (each float4 covers w0..w0+3) ----
    float4 Kv[25];
#pragma unroll
    for (int t = 0; t < 25; ++t) {
        Kv[t] = *reinterpret_cast<const float4*>(K + (t * H + h) * W + w0);
    }

    const bool wl = (w0 >= 4);        // left halo float4 in-bounds?
    const bool wr = (w0 + 4 < W);     // right halo float4 in-bounds?
    const float4 z4 = make_float4(0.f, 0.f, 0.f, 0.f);

#pragma unroll
    for (int bb = 0; bb < B_CHUNK; ++bb) {
        const int b = chunk * B_CHUNK + bb;
        const float dtb = dt[b];
        const float* fb = f + b * (H * W);

        float acc0 = 0.f, acc1 = 0.f, acc2 = 0.f, acc3 = 0.f;
        float fc0 = 0.f, fc1 = 0.f, fc2 = 0.f, fc3 = 0.f;

#pragma unroll
        for (int i = 0; i < KS; ++i) {
            const int hh = h + i - 2;                       // padded row index
            const bool rv = (hh >= 0) && (hh < H);
            const float* row = fb + hh * W;

            // buf covers columns w0-4 .. w0+7 (12 floats); taps use [2..10]
            const float4 rL = (rv && wl) ? *reinterpret_cast<const float4*>(row + w0 - 4) : z4;
            const float4 rC = rv         ? *reinterpret_cast<const float4*>(row + w0)     : z4;
            const float4 rR = (rv && wr) ? *reinterpret_cast<const float4*>(row + w0 + 4) : z4;
            const float buf[12] = { rL.x, rL.y, rL.z, rL.w,
                                    rC.x, rC.y, rC.z, rC.w,
                                    rR.x, rR.y, rR.z, rR.w };

            if (i == 2) { fc0 = buf[4]; fc1 = buf[5]; fc2 = buf[6]; fc3 = buf[7]; }

#pragma unroll
            for (int j = 0; j < KS; ++j) {
                // output col p needs f col (w0+p) + j - 2 -> buf[p + j + 2]
                const float4 kv = Kv[i * KS + j];
                acc0 += kv.x * buf[j + 2];
                acc1 += kv.y * buf[j + 3];
                acc2 += kv.z * buf[j + 4];
                acc3 += kv.w * buf[j + 5];
            }
        }

        float4 o;
        o.x = fmaxf(fc0 + acc0 * dtb, 0.f);
        o.y = fmaxf(fc1 + acc1 * dtb, 0.f);
        o.z = fmaxf(fc2 + acc2 * dtb, 0.f);
        o.w = fmaxf(fc3 + acc3 * dtb, 0.f);
        *reinterpret_cast<float4*>(out + (b * H + h) * W + w0) = o;
    }
}

extern "C" void kernel_launch(void* const* d_in, const int* in_sizes, int n_in,
                              void* d_out, int out_size, void* d_ws, size_t ws_size,
                              hipStream_t stream) {
    const float* f  = (const float*)d_in[0];   // (32,512,512)
    const float* K  = (const float*)d_in[1];   // (5,5,512,512)
    const float* dt = (const float*)d_in[2];   // (32,)
    float* out = (float*)d_out;

    dim3 block(256);
    dim3 grid(BATCH / B_CHUNK, H / 2);         // (4, 256)
    op2d_kernel<<<grid, block, 0, stream>>>(f, K, dt, out);
}

// Round 2
// 124.054 us; speedup vs baseline: 1.3653x; 1.3653x over previous
//
#include <hip/hip_runtime.h>

#define H 512
#define W 512
#define BATCH 32
#define KS 5
#define B_CHUNK 8          // batches per block; 32/8 = 4 chunks across grid.x
#define LROW 520           // padded LDS row: [4 zero][512 data][4 zero]
#define LBUF (6 * LROW)    // 6 rows per buffer = 3120 floats

typedef const __attribute__((address_space(1))) void gv_t;
typedef __attribute__((address_space(3))) void lv_t;

// Async global->LDS, 16 B per lane. lds_dst must be wave-uniform; HW scatters
// to lds_dst + lane*16. src is the per-lane global address.
__device__ __forceinline__ void async_cp16(const float* src, float* lds_dst) {
    __builtin_amdgcn_global_load_lds((gv_t*)src, (lv_t*)lds_dst, 16, 0, 0);
}

// Issue the 12 KB f-tile (6 rows x 512 floats) for one batch into ldsbuf.
// 12 chunks of 1 KB (64 lanes x 16 B); wave w takes chunks 3w..3w+2.
// Rows outside [0,H) are skipped (their LDS rows stay zero).
__device__ __forceinline__ void prefetch_tile(const float* __restrict__ fb,
                                              float* ldsbuf,
                                              int wave, int lane, int h0) {
#pragma unroll
    for (int k = 0; k < 3; ++k) {
        const int c    = wave * 3 + k;   // 0..11
        const int r    = c >> 1;         // tile row 0..5
        const int half = c & 1;          // which 1 KB half of the row
        const int gr   = h0 - 2 + r;     // global f row
        if (gr >= 0 && gr < H) {
            const float* src = fb + gr * W + half * 256 + lane * 4;
            float* dst = ldsbuf + r * LROW + 4 + half * 256;  // wave-uniform, 16B-aligned
            async_cp16(src, dst);
        }
    }
}

// Block: 256 threads = 2 output rows x 512 cols (4 cols/thread). Loops over 8
// batches; K taps live in 100 VGPRs; f tiles double-buffered in LDS with async
// prefetch one batch ahead.
__global__ __launch_bounds__(256, 2) void op2d_kernel(
    const float* __restrict__ f,   // (B,H,W)
    const float* __restrict__ K,   // (5,5,H,W)
    const float* __restrict__ dt,  // (B,)
    float* __restrict__ out)       // (B,H,W)
{
    __shared__ float lds[2 * LBUF];

    const int tid  = threadIdx.x;
    const int lane = tid & 63;
    const int wave = tid >> 6;
    const int w0   = (tid & 127) * 4;          // 0..508
    const int lr   = tid >> 7;                 // 0 or 1: local output row
    const int h0   = blockIdx.y * 2;
    const int h    = h0 + lr;
    const int chunk = blockIdx.x;              // batch group 0..3

    // Zero both buffers (covers the column pads and any invalid halo rows).
#pragma unroll
    for (int i = tid; i < 2 * LBUF; i += 256) lds[i] = 0.f;

    // ---- cache 25 per-pixel kernel taps in registers (coalesced float4) ----
    float4 Kv[25];
#pragma unroll
    for (int t = 0; t < 25; ++t) {
        Kv[t] = *reinterpret_cast<const float4*>(K + (t * H + h) * W + w0);
    }

    __syncthreads();   // zeros visible to all waves before any async load lands

    const float* fb0 = f + (size_t)(chunk * B_CHUNK) * H * W;
    prefetch_tile(fb0, lds, wave, lane, h0);   // batch 0 -> buffer 0

#pragma unroll
    for (int bb = 0; bb < B_CHUNK; ++bb) {
        // __syncthreads drains vmcnt(0): exactly the wait for batch bb's tile,
        // which has had a full compute phase in flight. Also joins waves so the
        // other buffer is safe to overwrite.
        __syncthreads();

        const int cur = bb & 1;
        if (bb + 1 < B_CHUNK) {
            prefetch_tile(fb0 + (size_t)(bb + 1) * H * W,
                          lds + (1 - cur) * LBUF, wave, lane, h0);
        }

        const int b   = chunk * B_CHUNK + bb;
        const float dtb = dt[b];
        const float* Lb = lds + cur * LBUF;

        float acc0 = 0.f, acc1 = 0.f, acc2 = 0.f, acc3 = 0.f;
        float fc0 = 0.f, fc1 = 0.f, fc2 = 0.f, fc3 = 0.f;

#pragma unroll
        for (int i = 0; i < KS; ++i) {
            const int tr = lr + i;                       // tile row for this tap row
            const float* row = Lb + tr * LROW + w0;      // padded: covers cols w0-4..w0+7
            const float4 ra = *reinterpret_cast<const float4*>(row);      // cols w0-4..w0-1
            const float4 rb = *reinterpret_cast<const float4*>(row + 4);  // cols w0  ..w0+3
            const float4 rc = *reinterpret_cast<const float4*>(row + 8);  // cols w0+4..w0+7
            const float buf[12] = { ra.x, ra.y, ra.z, ra.w,
                                    rb.x, rb.y, rb.z, rb.w,
                                    rc.x, rc.y, rc.z, rc.w };

            if (i == 2) { fc0 = rb.x; fc1 = rb.y; fc2 = rb.z; fc3 = rb.w; }

#pragma unroll
            for (int j = 0; j < KS; ++j) {
                const float4 kv = Kv[i * KS + j];
                acc0 += kv.x * buf[j + 2];
                acc1 += kv.y * buf[j + 3];
                acc2 += kv.z * buf[j + 4];
                acc3 += kv.w * buf[j + 5];
            }
        }

        float4 o;
        o.x = fmaxf(fc0 + acc0 * dtb, 0.f);
        o.y = fmaxf(fc1 + acc1 * dtb, 0.f);
        o.z = fmaxf(fc2 + acc2 * dtb, 0.f);
        o.w = fmaxf(fc3 + acc3 * dtb, 0.f);
        *reinterpret_cast<float4*>(out + ((size_t)b * H + h) * W + w0) = o;
    }
}

extern "C" void kernel_launch(void* const* d_in, const int* in_sizes, int n_in,
                              void* d_out, int out_size, void* d_ws, size_t ws_size,
                              hipStream_t stream) {
    const float* f  = (const float*)d_in[0];   // (32,512,512)
    const float* K  = (const float*)d_in[1];   // (5,5,512,512)
    const float* dt = (const float*)d_in[2];   // (32,)
    float* out = (float*)d_out;

    dim3 block(256);
    dim3 grid(BATCH / B_CHUNK, H / 2);         // (4, 256)
    op2d_kernel<<<grid, block, 0, stream>>>(f, K, dt, out);
}